// Round 22
// baseline (202.996 us; speedup 1.0000x reference)
//
#include <hip/hip_runtime.h>

// output element offsets (f32 elements)
#define OUT_X0   0
#define OUT_EMB  16777216
#define OUT_OPC  16781312
#define OUT_LOSS 16879616

// small-buffer byte offsets (relative to `small` base)
#define OFF_GFEAT 0            // 8192     u32 float-bits [16][128]
#define OFF_POOL  8192         // 65536    u32 float-bits [16][1024]
#define OFF_GCON  73728        // 65536    f32 [16][1024]
#define OFF_EMB   139264       // 16384    f32 [16][256]
#define OFF_HD1   155648       // 32768    f32 [16][512]
#define OFF_HD2   188416       // 65536    f32 [16][1024]
#define OFF_H3    253952       // 393216   f32 [16][6144]
#define OFF_OPC   647168       // 393216   f32 [16][6144]
#define OFF_D1M   1040384      // 262144   u32 [16][4096]
#define OFF_D2M   1302528      // 131072   u32 [16][2048]
#define OFF_PS    1433600      // 384      f32 [96]
#define OFF_W3BF  1433984      // 524288   bf16 w3 [1024][256]
#define OFF_CNT   1958272      // 4        int counter (sum_loss)
#define OFF_CNT2  1958276      // 4        int counter (decoder gsync)
#define H2_BYTES  (16u*1024*1024)   // bf16 h2 [65536][128] at ws+0 (big path)

typedef short short8 __attribute__((ext_vector_type(8)));
typedef float f32x4  __attribute__((ext_vector_type(4)));
typedef float f32x2  __attribute__((ext_vector_type(2)));

__device__ __forceinline__ unsigned short f2bf(float f){
  unsigned u = __float_as_uint(f);
  return (unsigned short)((u + 0x7FFFu + ((u >> 16) & 1u)) >> 16);
}

// packed dual-FP32 FMA: d = a*b + c per half (CDNA VOP3P)
__device__ __forceinline__ f32x2 pkfma(f32x2 a, f32x2 b, f32x2 c){
  f32x2 d;
  asm("v_pk_fma_f32 %0, %1, %2, %3" : "=v"(d) : "v"(a), "v"(b), "v"(c));
  return d;
}

// ------- conv1+conv2 via MFMA + folded w3-cvt + folded init -------
// bid 0..114: init fills. 115..626: conv (16 b x 32 pt-tiles). 627..1138: w3 cvt.
__global__ __launch_bounds__(256) void conv12_mfma(
    const float* __restrict__ in_pc,
    const float* __restrict__ w1, const float* __restrict__ b1,
    const float* __restrict__ w2, const float* __restrict__ b2,
    float* __restrict__ x0, unsigned short* __restrict__ h2b,
    unsigned* __restrict__ gfeatU,
    const float* __restrict__ w3, unsigned* __restrict__ w3bf,
    char* __restrict__ small)
{
  __shared__ unsigned short w2s[8192];   // [128 ch][64 c] bf16, XOR-swizzled
  __shared__ unsigned short h1s[8192];   // [128 pt][64 c] bf16, XOR-swizzled
  __shared__ float b2s[128];
  __shared__ unsigned gmax[128];
  int tid = threadIdx.x, bid = blockIdx.x;
  if (bid < 115){  // init: gfeat+pooled=0, d1m/d2m=0x7F, cnt=cnt2=0
    int i = bid*256 + tid;
    if (i < 4608) ((uint4*)(small + OFF_GFEAT))[i] = make_uint4(0u,0u,0u,0u);
    int j = i - 4608;
    if (j >= 0 && j < 24576)
      ((uint4*)(small + OFF_D1M))[j] =
        make_uint4(0x7F7F7F7Fu,0x7F7F7F7Fu,0x7F7F7F7Fu,0x7F7F7F7Fu);
    if (i == 29184) *(int*)(small + OFF_CNT) = 0;
    if (i == 29185) *(int*)(small + OFF_CNT2) = 0;
    return;
  }
  if (bid >= 627){   // w3 f32->bf16: 512*256 float2 = 131072
    int i = (bid-627)*256 + tid;
    float2 v = ((const float2*)w3)[i];
    w3bf[i] = (unsigned)f2bf(v.x) | ((unsigned)f2bf(v.y)<<16);
    return;
  }
  int cb = bid - 115;
  int b = cb >> 5;
  int nt0 = (cb & 31)*128;
  for (int i = tid; i < 2048; i += 256){
    int ch = i >> 4, q = i & 15;
    float4 v = ((const float4*)w2)[i];
    unsigned lo = (unsigned)f2bf(v.x) | ((unsigned)f2bf(v.y)<<16);
    unsigned hi = (unsigned)f2bf(v.z) | ((unsigned)f2bf(v.w)<<16);
    int byte = (ch*128 + q*8) ^ ((ch&7)<<4);
    *(uint2*)((char*)w2s + byte) = make_uint2(lo, hi);
  }
  if (tid < 128){ b2s[tid] = b2[tid]; gmax[tid] = 0u; }
  { // h1: 2 threads per point, 32 channels each
    int pt = tid & 127;
    int qb = (tid >> 7) * 16;
    int idx = b*4096 + nt0 + pt;
    const float* p = in_pc + (size_t)idx*3;
    float px=p[0], py=p[1], pz=p[2];
    unsigned hp[16];
    #pragma unroll
    for (int q=0;q<16;q++){
      int c = (qb + q)*2;
      float v0 = fmaxf(fmaf(w1[c*3  ],px, fmaf(w1[c*3+1],py, fmaf(w1[c*3+2],pz, b1[c  ]))), 0.f);
      float v1 = fmaxf(fmaf(w1[c*3+3],px, fmaf(w1[c*3+4],py, fmaf(w1[c*3+5],pz, b1[c+1]))), 0.f);
      hp[q] = (unsigned)f2bf(v0) | ((unsigned)f2bf(v1)<<16);
    }
    #pragma unroll
    for (int t=0;t<4;t++){
      int byte = (pt*128 + qb*4 + t*16) ^ ((pt&7)<<4);
      *(uint4*)((char*)h1s + byte) = make_uint4(hp[t*4],hp[t*4+1],hp[t*4+2],hp[t*4+3]);
    }
  }
  __syncthreads();
  int lane = tid & 63, w = tid >> 6;
  int g = lane >> 4, p15 = lane & 15;
  f32x4 acc[8][2] = {};
  #pragma unroll
  for (int ks=0; ks<2; ks++){
    int kb = (ks*32 + g*8)*2;
    short8 bfr[2];
    #pragma unroll
    for (int nf=0;nf<2;nf++){
      int pt = w*32 + nf*16 + p15;
      bfr[nf] = *(const short8*)((const char*)h1s + ((pt*128 + kb) ^ ((pt&7)<<4)));
    }
    #pragma unroll
    for (int mf=0;mf<8;mf++){
      int ch = mf*16 + p15;
      short8 af = *(const short8*)((const char*)w2s + ((ch*128 + kb) ^ ((ch&7)<<4)));
      acc[mf][0] = __builtin_amdgcn_mfma_f32_16x16x32_bf16(af, bfr[0], acc[mf][0], 0,0,0);
      acc[mf][1] = __builtin_amdgcn_mfma_f32_16x16x32_bf16(af, bfr[1], acc[mf][1], 0,0,0);
    }
  }
  int n_base = nt0 + w*32;
  #pragma unroll
  for (int mf=0; mf<8; mf++){
    int ch0 = mf*16 + g*4;
    float bias[4];
    #pragma unroll
    for (int j=0;j<4;j++) bias[j] = b2s[ch0+j];
    float vm[4] = {0.f,0.f,0.f,0.f};
    #pragma unroll
    for (int nf=0; nf<2; nf++){
      int n = n_base + nf*16 + p15;
      float v[4];
      #pragma unroll
      for (int j=0;j<4;j++){
        v[j] = fmaxf(acc[mf][nf][j] + bias[j], 0.f);
        vm[j] = fmaxf(vm[j], v[j]);
        x0[((size_t)(b*256 + ch0 + j))*4096 + n] = v[j];
      }
      unsigned lo = (unsigned)f2bf(v[0]) | ((unsigned)f2bf(v[1])<<16);
      unsigned hi = (unsigned)f2bf(v[2]) | ((unsigned)f2bf(v[3])<<16);
      *(uint2*)&h2b[((size_t)(b*4096 + n))*128 + ch0] = make_uint2(lo, hi);
    }
    #pragma unroll
    for (int j=0;j<4;j++){
      float m = vm[j];
      m = fmaxf(m, __shfl_xor(m,1));
      m = fmaxf(m, __shfl_xor(m,2));
      m = fmaxf(m, __shfl_xor(m,4));
      m = fmaxf(m, __shfl_xor(m,8));
      if (p15==0) atomicMax(&gmax[ch0+j], __float_as_uint(m));
    }
  }
  __syncthreads();
  if (tid < 128) atomicMax(&gfeatU[b*128 + tid], gmax[tid]);
}

// ---- gcon wave-per-output: 128 blocks x 8 outputs; reads 8KB gfeatU ----
__global__ __launch_bounds__(256) void gcon_k(
    const unsigned* __restrict__ gfeatU,
    const float* __restrict__ w3, const float* __restrict__ b3,
    float* __restrict__ gcon)
{
  __shared__ float gf[2048];
  int tid = threadIdx.x, bid = blockIdx.x;
  for (int i=tid;i<2048;i+=256) gf[i] = __uint_as_float(gfeatU[i]);
  __syncthreads();
  int w = tid >> 6, lane = tid & 63;
  #pragma unroll
  for (int j=0;j<2;j++){
    int o = bid*8 + w*2 + j;
    float2 wv = *(const float2*)&w3[(size_t)o*256 + 128 + lane*2];
    float bias = b3[o];
    #pragma unroll
    for (int b=0;b<16;b++){
      float v = gf[b*128 + lane*2]*wv.x + gf[b*128 + lane*2 + 1]*wv.y;
      #pragma unroll
      for (int off=32; off; off>>=1) v += __shfl_xor(v, off);
      if (lane==0) gcon[b*1024+o] = bias + v;
    }
  }
}

// ------- fused: conv3 MFMA+pool (bids 0..511) | x0 gfeat-bcast (512..4607) -------
__global__ __launch_bounds__(512) void conv3_bcast(
    const unsigned short* __restrict__ h2b, const unsigned short* __restrict__ w3b,
    const float* __restrict__ gcon, unsigned* __restrict__ pooled,
    const unsigned* __restrict__ gfeatU, float* __restrict__ x0)
{
  __shared__ unsigned short Al[128*128];
  __shared__ unsigned short Bl[128*128];
  int tid = threadIdx.x, bid = blockIdx.x;
  if (bid >= 512){
    unsigned U = (unsigned)(bid-512)*512 + tid;
    int n4 = U & 1023, c = (U >> 10) & 127, b = U >> 17;
    float g = __uint_as_float(gfeatU[b*128+c]);
    float4 v = {g,g,g,g};
    ((float4*)x0)[(((size_t)b*256 + 128 + c)*4096)/4 + n4] = v;
    return;
  }
  int mt = bid & 31, b = bid >> 5;
  {
    const uint4* src = (const uint4*)(h2b + ((size_t)b*4096 + mt*128)*128);
    #pragma unroll
    for (int i=0;i<4;i++){
      int idx = i*512 + tid;
      int r = idx>>4, kc = idx&15;
      uint4 v = src[idx];
      int byte = (r*256 + kc*16) ^ ((r&7)<<4);
      *(uint4*)((char*)Al + byte) = v;
    }
  }
  int lane = tid & 63, wid = tid >> 6;
  int wm = wid >> 2, wn = wid & 3;
  int mbase = wm*64, nbase = wn*32;
  for (int nt=0; nt<8; nt++){
    if (nt) __syncthreads();
    {
      #pragma unroll
      for (int i=0;i<4;i++){
        int idx = i*512 + tid;
        int c = idx>>4, kc = idx&15;
        uint4 v = *(const uint4*)(w3b + ((size_t)(nt*128+c)*256 + kc*8));
        int byte = (c*256 + kc*16) ^ ((c&7)<<4);
        *(uint4*)((char*)Bl + byte) = v;
      }
    }
    __syncthreads();
    f32x4 acc[4][2] = {};
    #pragma unroll
    for (int ks=0;ks<4;ks++){
      int kb = (ks*32 + (lane>>4)*8)*2;
      short8 af[4], bfr[2];
      #pragma unroll
      for (int mi=0;mi<4;mi++){
        int row = mbase + mi*16 + (lane&15);
        af[mi] = *(const short8*)((const char*)Al + ((row*256 + kb) ^ ((row&7)<<4)));
      }
      #pragma unroll
      for (int ni=0;ni<2;ni++){
        int col = nbase + ni*16 + (lane&15);
        bfr[ni] = *(const short8*)((const char*)Bl + ((col*256 + kb) ^ ((col&7)<<4)));
      }
      #pragma unroll
      for (int mi=0;mi<4;mi++){
        #pragma unroll
        for (int ni=0;ni<2;ni++)
          acc[mi][ni] = __builtin_amdgcn_mfma_f32_16x16x32_bf16(af[mi], bfr[ni], acc[mi][ni], 0,0,0);
      }
    }
    #pragma unroll
    for (int ni=0;ni<2;ni++){
      int o = nt*128 + nbase + ni*16 + (lane&15);
      float g = gcon[b*1024 + o];
      float m = 0.f;
      #pragma unroll
      for (int mi=0;mi<4;mi++){
        f32x4 a = acc[mi][ni];
        #pragma unroll
        for (int r=0;r<4;r++){ float v = a[r]+g; m = fmaxf(m, v); }
      }
      m = fmaxf(m, 0.f);
      m = fmaxf(m, __shfl_xor(m, 16));
      m = fmaxf(m, __shfl_xor(m, 32));
      if (lane < 16) atomicMax(&pooled[(size_t)b*1024+o], __float_as_uint(m));
    }
  }
}

// ---- wave dot: out[b][o] for all 16 b, one wave; K multiple of 256 floats ----
__device__ __forceinline__ void fc16_dot(
    const float* __restrict__ A, const float* __restrict__ Wr, float bias,
    bool relu, float* __restrict__ out, float* __restrict__ out2,
    int K, int O, int o, int lane)
{
  float acc[16];
  #pragma unroll
  for (int b=0;b<16;b++) acc[b]=0.f;
  for (int k = lane*4; k < K; k += 256){
    float4 wv = *(const float4*)&Wr[k];
    #pragma unroll
    for (int b=0;b<16;b++){
      float4 av = *(const float4*)&A[(size_t)b*K + k];
      acc[b] += wv.x*av.x + wv.y*av.y + wv.z*av.z + wv.w*av.w;
    }
  }
  #pragma unroll
  for (int b=0;b<16;b++){
    float v = acc[b];
    #pragma unroll
    for (int off=32; off; off>>=1) v += __shfl_xor(v, off);
    if (lane==0){
      v += bias;
      if (relu) v = fmaxf(v, 0.f);
      out[(size_t)b*O+o] = v;
      if (out2) out2[(size_t)b*O+o] = v;
    }
  }
}

// ---- counter grid-sync (256 co-resident blocks, monotonic counter) ----
__device__ __forceinline__ void gsync(int* c, int target){
  __syncthreads();
  if (threadIdx.x==0){
    __threadfence();
    atomicAdd(c, 1);
    while (atomicAdd(c, 0) < target) __builtin_amdgcn_s_sleep(8);
  }
  __syncthreads();
}

// ---- fused decoder: fc_enc -> fc1 -> fc2 -> fc3 -> layernorm (256 blocks) ----
__global__ __launch_bounds__(256) void decoder_k(
    const float* __restrict__ pooled,
    const float* __restrict__ wenc, const float* __restrict__ benc,
    const float* __restrict__ wf1, const float* __restrict__ bfc1,
    const float* __restrict__ wf2, const float* __restrict__ bfc2,
    const float* __restrict__ wf3, const float* __restrict__ bfc3,
    const float* __restrict__ lng, const float* __restrict__ lnb,
    float* __restrict__ emb, float* __restrict__ hd1, float* __restrict__ hd2,
    float* __restrict__ h3, float* __restrict__ opc,
    float* __restrict__ outbuf, int* __restrict__ cnt2)
{
  int tid = threadIdx.x, lane = tid & 63;
  int gw = blockIdx.x*4 + (tid >> 6);      // 1024 waves
  // stage A: emb = pooled @ wenc^T (+bias), O=256 K=1024
  if (gw < 256)
    fc16_dot(pooled, wenc + (size_t)gw*1024, benc[gw], false,
             emb, outbuf + OUT_EMB, 1024, 256, gw, lane);
  gsync(cnt2, 256);
  // stage B: hd1 = relu(emb @ wf1^T), O=512 K=256
  if (gw < 512)
    fc16_dot(emb, wf1 + (size_t)gw*256, bfc1[gw], true,
             hd1, nullptr, 256, 512, gw, lane);
  gsync(cnt2, 512);
  // stage C: hd2 = relu(hd1 @ wf2^T), O=1024 K=512
  fc16_dot(hd1, wf2 + (size_t)gw*512, bfc2[gw], true,
           hd2, nullptr, 512, 1024, gw, lane);
  gsync(cnt2, 768);
  // stage D: h3 = hd2 @ wf3^T, O=6144 K=1024 (6 outputs/wave)
  #pragma unroll
  for (int j=0;j<6;j++){
    int o = gw*6 + j;
    fc16_dot(hd2, wf3 + (size_t)o*1024, bfc3[o], false,
             h3, nullptr, 1024, 6144, o, lane);
  }
  gsync(cnt2, 1024);
  // stage E: layernorm rows (blocks 0..15)
  int b = blockIdx.x;
  if (b >= 16) return;
  const float* x = h3 + b*6144;
  float s=0.f, s2=0.f;
  for (int i=tid;i<6144;i+=256){ float v=x[i]; s+=v; s2+=v*v; }
  for (int off=32; off; off>>=1){ s += __shfl_xor(s,off); s2 += __shfl_xor(s2,off); }
  __shared__ float red[8];
  int wid = tid>>6;
  if (lane==0){ red[wid]=s; red[4+wid]=s2; }
  __syncthreads();
  s  = red[0]+red[1]+red[2]+red[3];
  s2 = red[4]+red[5]+red[6]+red[7];
  float mu  = s * (1.f/6144.f);
  float var = s2 * (1.f/6144.f) - mu*mu;
  float inv = rsqrtf(var + 1e-5f);
  for (int i=tid;i<6144;i+=256){
    float v = (x[i]-mu)*inv*lng[i] + lnb[i];
    opc[b*6144+i] = v;
    outbuf[OUT_OPC + b*6144+i] = v;
  }
}

// ---- fallback (small ws) kernels ----
__global__ __launch_bounds__(256) void conv12_f32(
    const float* __restrict__ in_pc,
    const float* __restrict__ w1, const float* __restrict__ b1,
    const float* __restrict__ w2, const float* __restrict__ b2,
    float* __restrict__ x0, unsigned* __restrict__ gfeatU)
{
  __shared__ unsigned gmax[32];
  int tid = threadIdx.x;
  if (tid < 32) gmax[tid] = 0u;
  __syncthreads();
  int idx = blockIdx.x*256 + tid;
  int b = idx >> 12, n = idx & 4095;
  int gy = blockIdx.y;
  int lane = tid & 63;
  const float* p = in_pc + (size_t)idx*3;
  float px=p[0], py=p[1], pz=p[2];
  float h1[64];
  #pragma unroll
  for (int c=0;c<64;c++)
    h1[c] = fmaxf(w1[c*3]*px + w1[c*3+1]*py + w1[c*3+2]*pz + b1[c], 0.f);
  #pragma unroll
  for (int j=0;j<32;j++){
    int o = gy*32 + j;
    float a = b2[o];
    #pragma unroll
    for (int c=0;c<64;c++) a += w2[o*64+c]*h1[c];
    a = fmaxf(a, 0.f);
    x0[((size_t)b*256 + o)*4096 + n] = a;
    float m = a;
    #pragma unroll
    for (int off=32; off; off>>=1) m = fmaxf(m, __shfl_xor(m, off));
    if (lane==0) atomicMax(&gmax[j], __float_as_uint(m));
  }
  __syncthreads();
  if (tid < 32) atomicMax(&gfeatU[b*128 + gy*32 + tid], gmax[tid]);
}

__global__ __launch_bounds__(256) void bcast_gcon(
    const unsigned* __restrict__ gfeatU, float* __restrict__ x0,
    const float* __restrict__ w3, const float* __restrict__ b3,
    float* __restrict__ gcon)
{
  __shared__ float gf[2048];
  int tid = threadIdx.x;
  if (blockIdx.x < 8192){
    unsigned U = blockIdx.x*256 + tid;
    int n4 = U & 1023, c = (U >> 10) & 127, b = U >> 17;
    float g = __uint_as_float(gfeatU[b*128+c]);
    float4 v = {g,g,g,g};
    ((float4*)x0)[(((size_t)b*256 + 128 + c)*4096)/4 + n4] = v;
  } else {
    for (int i=tid;i<2048;i+=256) gf[i] = __uint_as_float(gfeatU[i]);
    __syncthreads();
    int o = (blockIdx.x - 8192)*256 + tid;
    float bias = b3[o];
    float acc[16];
    #pragma unroll
    for (int b=0;b<16;b++) acc[b]=bias;
    for (int c=0;c<128;c++){
      float wv = w3[(size_t)o*256 + 128 + c];
      #pragma unroll
      for (int b=0;b<16;b++) acc[b] += gf[b*128+c]*wv;
    }
    #pragma unroll
    for (int b=0;b<16;b++) gcon[b*1024+o] = acc[b];
  }
}

__global__ __launch_bounds__(256) void conv3n(
    const float* __restrict__ x0, const unsigned* __restrict__ gfeatU,
    const float* __restrict__ w3, const float* __restrict__ b3,
    unsigned* __restrict__ pooled)
{
  __shared__ float wrow[8][256];
  int b = blockIdx.x >> 7, og = (blockIdx.x & 127)*8, tid = threadIdx.x;
  for (int i=tid;i<2048;i+=256){ int j=i>>8, c=i&255; wrow[j][c]=w3[(size_t)(og+j)*256+c]; }
  __syncthreads();
  float gconst[8];
  #pragma unroll
  for (int j=0;j<8;j++){
    float g = b3[og+j];
    for (int c=0;c<128;c++) g += __uint_as_float(gfeatU[b*128+c])*wrow[j][128+c];
    gconst[j] = g;
  }
  const float* xb = x0 + (size_t)b*256*4096;
  float m[8];
  #pragma unroll
  for (int j=0;j<8;j++) m[j]=0.f;
  for (int n=tid;n<4096;n+=256){
    float v[8];
    #pragma unroll
    for (int j=0;j<8;j++) v[j]=gconst[j];
    for (int c=0;c<128;c++){
      float xv = xb[(size_t)c*4096 + n];
      #pragma unroll
      for (int j=0;j<8;j++) v[j] += xv*wrow[j][c];
    }
    #pragma unroll
    for (int j=0;j<8;j++) m[j] = fmaxf(m[j], v[j]);
  }
  #pragma unroll
  for (int j=0;j<8;j++){
    float v = m[j];
    for (int off=32; off; off>>=1) v = fmaxf(v, __shfl_xor(v, off));
    if ((tid&63)==0) atomicMax(&pooled[(size_t)b*1024+og+j], __float_as_uint(v));
  }
}

template<bool RELU>
__global__ __launch_bounds__(256) void fc_wave16(
    const float* __restrict__ A, const float* __restrict__ W,
    const float* __restrict__ bias, float* __restrict__ out,
    float* __restrict__ out2, int K, int O)
{
  int lane = threadIdx.x & 63, w = threadIdx.x >> 6;
  int o = blockIdx.x*4 + w;
  fc16_dot(A, W + (size_t)o*K, bias[o], RELU, out, out2, K, O, o, lane);
}

__global__ __launch_bounds__(256) void lnorm(
    const float* __restrict__ h3, const float* __restrict__ g,
    const float* __restrict__ be, float* __restrict__ outf,
    float* __restrict__ outb)
{
  int b = blockIdx.x, tid = threadIdx.x;
  const float* x = h3 + b*6144;
  float s=0.f, s2=0.f;
  for (int i=tid;i<6144;i+=256){ float v=x[i]; s+=v; s2+=v*v; }
  for (int off=32; off; off>>=1){ s += __shfl_xor(s,off); s2 += __shfl_xor(s2,off); }
  __shared__ float red[8];
  int lane = tid&63, wid = tid>>6;
  if (lane==0){ red[wid]=s; red[4+wid]=s2; }
  __syncthreads();
  s  = red[0]+red[1]+red[2]+red[3];
  s2 = red[4]+red[5]+red[6]+red[7];
  float mu  = s * (1.f/6144.f);
  float var = s2 * (1.f/6144.f) - mu*mu;
  float inv = rsqrtf(var + 1e-5f);
  for (int i=tid;i<6144;i+=256){
    float v = (x[i]-mu)*inv*g[i] + be[i];
    outf[b*6144+i] = v;
    outb[b*6144+i] = v;
  }
}

// ---- chamfer: 512 targets staged/block; packed dual-FP32 FMA ----
__global__ __launch_bounds__(256) void chamfer_all(
    const float* __restrict__ in_pc, const float* __restrict__ opc,
    unsigned* __restrict__ d1m, unsigned* __restrict__ d2m)
{
  __shared__ float sX[512], sY[512], sZ[512], sQ[512];
  int bid = blockIdx.x, tid = threadIdx.x;
  const float* stage;
  const float* qry;
  unsigned* outp;
  if (bid < 1024){
    int xt = bid & 15, b = (bid >> 4) & 15, mt = bid >> 8;
    stage = opc + b*6144 + mt*1536;
    qry   = in_pc + ((size_t)b*4096 + xt*256 + tid)*3;
    outp  = d1m + b*4096 + xt*256 + tid;
  } else {
    int r = bid - 1024;
    int xt = r & 7, b = (r >> 3) & 15, nt = r >> 7;
    stage = in_pc + ((size_t)b*4096 + nt*512)*3;
    qry   = opc + b*6144 + (xt*256 + tid)*3;
    outp  = d2m + b*2048 + xt*256 + tid;
  }
  for (int s = tid; s < 512; s += 256){
    const float* S = stage + s*3;
    float x=S[0], y=S[1], z=S[2];
    sX[s]=-2.f*x; sY[s]=-2.f*y; sZ[s]=-2.f*z; sQ[s]=x*x+y*y+z*z;
  }
  __syncthreads();
  float qx=qry[0], qy=qry[1], qz=qry[2];
  float p2 = qx*qx + qy*qy + qz*qz;
  f32x2 qxv = {qx,qx}, qyv = {qy,qy}, qzv = {qz,qz};
  float ma=3.0e38f, mb=3.0e38f, mc=3.0e38f, md=3.0e38f;
  #pragma unroll 4
  for (int i=0;i<128;i++){
    f32x4 X = *(const f32x4*)&sX[i*4];
    f32x4 Y = *(const f32x4*)&sY[i*4];
    f32x4 Z = *(const f32x4*)&sZ[i*4];
    f32x4 Q = *(const f32x4*)&sQ[i*4];
    f32x2 t0 = __builtin_shufflevector(Q,Q,0,1);
    f32x2 t1 = __builtin_shufflevector(Q,Q,2,3);
    t0 = pkfma(qzv, __builtin_shufflevector(Z,Z,0,1), t0);
    t1 = pkfma(qzv, __builtin_shufflevector(Z,Z,2,3), t1);
    t0 = pkfma(qyv, __builtin_shufflevector(Y,Y,0,1), t0);
    t1 = pkfma(qyv, __builtin_shufflevector(Y,Y,2,3), t1);
    t0 = pkfma(qxv, __builtin_shufflevector(X,X,0,1), t0);
    t1 = pkfma(qxv, __builtin_shufflevector(X,X,2,3), t1);
    ma = fminf(ma, t0.x); mb = fminf(mb, t0.y);
    mc = fminf(mc, t1.x); md = fminf(md, t1.y);
  }
  float d = fmaxf(p2 + fminf(fminf(ma,mb), fminf(mc,md)), 0.f);
  atomicMin(outp, __float_as_uint(d));
}

// ---- fused deterministic loss reduction (96 partials + last-block finish) ----
__global__ __launch_bounds__(256) void sum_loss(
    const unsigned* __restrict__ d1m, const unsigned* __restrict__ d2m,
    float* __restrict__ ps, int* __restrict__ cnt, float* __restrict__ out)
{
  int bid = blockIdx.x, tid = threadIdx.x;
  __shared__ float red[4];
  __shared__ int last;
  {
    const unsigned* src = (bid<64) ? (d1m + bid*1024) : (d2m + (size_t)(bid-64)*1024);
    float s = 0.f;
    for (int i=tid;i<1024;i+=256) s += __uint_as_float(src[i]);
    for (int off=32; off; off>>=1) s += __shfl_xor(s,off);
    if ((tid&63)==0) red[tid>>6]=s;
    __syncthreads();
    if (tid==0){
      ps[bid] = red[0]+red[1]+red[2]+red[3];
      __threadfence();
      last = (atomicAdd(cnt, 1) == 95);
    }
    __syncthreads();
  }
  if (!last) return;
  __threadfence();
  float v = 0.f;
  if (tid < 64) v = ps[tid] * (1.0f/65536.0f);
  else if (tid < 96) v = ps[tid] * (1.0f/32768.0f);
  for (int off=32; off; off>>=1) v += __shfl_xor(v,off);
  __syncthreads();
  if ((tid&63)==0) red[tid>>6]=v;
  __syncthreads();
  if (tid==0) out[0] = red[0]+red[1]+red[2]+red[3];
}

// ---------------- launch ----------------
extern "C" void kernel_launch(void* const* d_in, const int* in_sizes, int n_in,
                              void* d_out, int out_size, void* d_ws, size_t ws_size,
                              hipStream_t stream)
{
  (void)in_sizes; (void)n_in; (void)out_size;
  const float* in_pc = (const float*)d_in[0];
  const float* w1   = (const float*)d_in[1];
  const float* b1   = (const float*)d_in[2];
  const float* w2   = (const float*)d_in[3];
  const float* b2   = (const float*)d_in[4];
  const float* w3   = (const float*)d_in[5];
  const float* b3   = (const float*)d_in[6];
  const float* wenc = (const float*)d_in[7];
  const float* benc = (const float*)d_in[8];
  const float* wf1  = (const float*)d_in[9];
  const float* bfc1 = (const float*)d_in[10];
  const float* wf2  = (const float*)d_in[11];
  const float* bfc2 = (const float*)d_in[12];
  const float* wf3  = (const float*)d_in[13];
  const float* bfc3 = (const float*)d_in[14];
  const float* lng  = (const float*)d_in[15];
  const float* lnb  = (const float*)d_in[16];
  float* out = (float*)d_out;

  bool big = ws_size >= (size_t)(H2_BYTES + 3*1024*1024);
  char* ws = (char*)d_ws;
  unsigned short* h2b = (unsigned short*)ws;
  char* small = ws + (big ? H2_BYTES : 0);

  unsigned* gfeatU = (unsigned*)(small + OFF_GFEAT);
  float* pooled = (float*)(small + OFF_POOL);
  float* gcon = (float*)(small + OFF_GCON);
  float* emb  = (float*)(small + OFF_EMB);
  float* hd1  = (float*)(small + OFF_HD1);
  float* hd2  = (float*)(small + OFF_HD2);
  float* h3   = (float*)(small + OFF_H3);
  float* opc  = (float*)(small + OFF_OPC);
  unsigned* d1m = (unsigned*)(small + OFF_D1M);
  unsigned* d2m = (unsigned*)(small + OFF_D2M);
  float* ps   = (float*)(small + OFF_PS);
  unsigned short* w3b = (unsigned short*)(small + OFF_W3BF);
  int* cnt = (int*)(small + OFF_CNT);
  int* cnt2 = (int*)(small + OFF_CNT2);

  if (big){
    conv12_mfma<<<1139, 256, 0, stream>>>(in_pc, w1, b1, w2, b2, out, h2b, gfeatU,
                                          w3, (unsigned*)w3b, small);
    gcon_k<<<128, 256, 0, stream>>>(gfeatU, w3, b3, gcon);
    conv3_bcast<<<4608, 512, 0, stream>>>(h2b, w3b, gcon, (unsigned*)pooled,
                                          gfeatU, out);
    decoder_k<<<256, 256, 0, stream>>>(pooled, wenc, benc, wf1, bfc1, wf2, bfc2,
                                       wf3, bfc3, lng, lnb, emb, hd1, hd2, h3,
                                       opc, out, cnt2);
  } else {
    hipMemsetAsync(small + OFF_GFEAT, 0, 8192 + 65536, stream);
    hipMemsetAsync(small + OFF_D1M, 0x7F, 262144 + 131072, stream);
    hipMemsetAsync(small + OFF_CNT, 0, 8, stream);
    conv12_f32<<<dim3(256,4), 256, 0, stream>>>(in_pc, w1, b1, w2, b2, out, gfeatU);
    bcast_gcon<<<8196, 256, 0, stream>>>(gfeatU, out, w3, b3, gcon);
    conv3n<<<2048, 256, 0, stream>>>(out, gfeatU, w3, b3, (unsigned*)pooled);
    fc_wave16<false><<<64,   256, 0, stream>>>(pooled, wenc, benc, emb, out + OUT_EMB, 1024, 256);
    fc_wave16<true ><<<128,  256, 0, stream>>>(emb, wf1, bfc1, hd1, nullptr, 256, 512);
    fc_wave16<true ><<<256,  256, 0, stream>>>(hd1, wf2, bfc2, hd2, nullptr, 512, 1024);
    fc_wave16<false><<<1536, 256, 0, stream>>>(hd2, wf3, bfc3, h3, nullptr, 1024, 6144);
    lnorm<<<16, 256, 0, stream>>>(h3, lng, lnb, opc, out + OUT_OPC);
  }
  chamfer_all<<<2048, 256, 0, stream>>>(in_pc, opc, d1m, d2m);
  sum_loss<<<96, 256, 0, stream>>>(d1m, d2m, ps, cnt, out + OUT_LOSS);
}

// Round 23
// 155.947 us; speedup vs baseline: 1.3017x; 1.3017x over previous
//
#include <hip/hip_runtime.h>

// output element offsets (f32 elements)
#define OUT_X0   0
#define OUT_EMB  16777216
#define OUT_OPC  16781312
#define OUT_LOSS 16879616

// small-buffer byte offsets (relative to `small` base)
#define OFF_GFEAT 0            // 8192     u32 float-bits [16][128]
#define OFF_POOL  8192         // 65536    u32 float-bits [16][1024]
#define OFF_GCON  73728        // 65536    f32 [16][1024]
#define OFF_EMB   139264       // 16384    f32 [16][256]
#define OFF_HD1   155648       // 32768    f32 [16][512]
#define OFF_HD2   188416       // 65536    f32 [16][1024]
#define OFF_H3    253952       // 393216   f32 [16][6144]
#define OFF_OPC   647168       // 393216   f32 [16][6144]
#define OFF_D1M   1040384      // 262144   u32 [16][4096]
#define OFF_D2M   1302528      // 131072   u32 [16][2048]
#define OFF_PS    1433600      // 384      f32 [96]
#define OFF_W3BF  1433984      // 524288   bf16 w3 [1024][256]
#define OFF_CNT   1958272      // 4        int counter
#define H2_BYTES  (16u*1024*1024)   // bf16 h2 [65536][128] at ws+0 (big path)

typedef short short8 __attribute__((ext_vector_type(8)));
typedef float f32x4  __attribute__((ext_vector_type(4)));
typedef float f32x2  __attribute__((ext_vector_type(2)));

__device__ __forceinline__ unsigned short f2bf(float f){
  unsigned u = __float_as_uint(f);
  return (unsigned short)((u + 0x7FFFu + ((u >> 16) & 1u)) >> 16);
}

// packed dual-FP32 FMA: d = a*b + c per half (CDNA VOP3P)
__device__ __forceinline__ f32x2 pkfma(f32x2 a, f32x2 b, f32x2 c){
  f32x2 d;
  asm("v_pk_fma_f32 %0, %1, %2, %3" : "=v"(d) : "v"(a), "v"(b), "v"(c));
  return d;
}

// ------- conv1+conv2 via MFMA + folded w3-cvt + folded init -------
// bid 0..114: init fills. 115..626: conv (16 b x 32 pt-tiles). 627..1138: w3 cvt.
__global__ __launch_bounds__(256) void conv12_mfma(
    const float* __restrict__ in_pc,
    const float* __restrict__ w1, const float* __restrict__ b1,
    const float* __restrict__ w2, const float* __restrict__ b2,
    float* __restrict__ x0, unsigned short* __restrict__ h2b,
    unsigned* __restrict__ gfeatU,
    const float* __restrict__ w3, unsigned* __restrict__ w3bf,
    char* __restrict__ small)
{
  __shared__ unsigned short w2s[8192];   // [128 ch][64 c] bf16, XOR-swizzled
  __shared__ unsigned short h1s[8192];   // [128 pt][64 c] bf16, XOR-swizzled
  __shared__ float b2s[128];
  __shared__ unsigned gmax[128];
  int tid = threadIdx.x, bid = blockIdx.x;
  if (bid < 115){  // init: gfeat+pooled=0, d1m/d2m=0x7F, cnt=0
    int i = bid*256 + tid;
    if (i < 4608) ((uint4*)(small + OFF_GFEAT))[i] = make_uint4(0u,0u,0u,0u);
    int j = i - 4608;
    if (j >= 0 && j < 24576)
      ((uint4*)(small + OFF_D1M))[j] =
        make_uint4(0x7F7F7F7Fu,0x7F7F7F7Fu,0x7F7F7F7Fu,0x7F7F7F7Fu);
    if (i == 29184) *(int*)(small + OFF_CNT) = 0;
    return;
  }
  if (bid >= 627){   // w3 f32->bf16: 512*256 float2 = 131072
    int i = (bid-627)*256 + tid;
    float2 v = ((const float2*)w3)[i];
    w3bf[i] = (unsigned)f2bf(v.x) | ((unsigned)f2bf(v.y)<<16);
    return;
  }
  int cb = bid - 115;
  int b = cb >> 5;
  int nt0 = (cb & 31)*128;
  for (int i = tid; i < 2048; i += 256){
    int ch = i >> 4, q = i & 15;
    float4 v = ((const float4*)w2)[i];
    unsigned lo = (unsigned)f2bf(v.x) | ((unsigned)f2bf(v.y)<<16);
    unsigned hi = (unsigned)f2bf(v.z) | ((unsigned)f2bf(v.w)<<16);
    int byte = (ch*128 + q*8) ^ ((ch&7)<<4);
    *(uint2*)((char*)w2s + byte) = make_uint2(lo, hi);
  }
  if (tid < 128){ b2s[tid] = b2[tid]; gmax[tid] = 0u; }
  { // h1: 2 threads per point, 32 channels each
    int pt = tid & 127;
    int qb = (tid >> 7) * 16;
    int idx = b*4096 + nt0 + pt;
    const float* p = in_pc + (size_t)idx*3;
    float px=p[0], py=p[1], pz=p[2];
    unsigned hp[16];
    #pragma unroll
    for (int q=0;q<16;q++){
      int c = (qb + q)*2;
      float v0 = fmaxf(fmaf(w1[c*3  ],px, fmaf(w1[c*3+1],py, fmaf(w1[c*3+2],pz, b1[c  ]))), 0.f);
      float v1 = fmaxf(fmaf(w1[c*3+3],px, fmaf(w1[c*3+4],py, fmaf(w1[c*3+5],pz, b1[c+1]))), 0.f);
      hp[q] = (unsigned)f2bf(v0) | ((unsigned)f2bf(v1)<<16);
    }
    #pragma unroll
    for (int t=0;t<4;t++){
      int byte = (pt*128 + qb*4 + t*16) ^ ((pt&7)<<4);
      *(uint4*)((char*)h1s + byte) = make_uint4(hp[t*4],hp[t*4+1],hp[t*4+2],hp[t*4+3]);
    }
  }
  __syncthreads();
  int lane = tid & 63, w = tid >> 6;
  int g = lane >> 4, p15 = lane & 15;
  f32x4 acc[8][2] = {};
  #pragma unroll
  for (int ks=0; ks<2; ks++){
    int kb = (ks*32 + g*8)*2;
    short8 bfr[2];
    #pragma unroll
    for (int nf=0;nf<2;nf++){
      int pt = w*32 + nf*16 + p15;
      bfr[nf] = *(const short8*)((const char*)h1s + ((pt*128 + kb) ^ ((pt&7)<<4)));
    }
    #pragma unroll
    for (int mf=0;mf<8;mf++){
      int ch = mf*16 + p15;
      short8 af = *(const short8*)((const char*)w2s + ((ch*128 + kb) ^ ((ch&7)<<4)));
      acc[mf][0] = __builtin_amdgcn_mfma_f32_16x16x32_bf16(af, bfr[0], acc[mf][0], 0,0,0);
      acc[mf][1] = __builtin_amdgcn_mfma_f32_16x16x32_bf16(af, bfr[1], acc[mf][1], 0,0,0);
    }
  }
  int n_base = nt0 + w*32;
  #pragma unroll
  for (int mf=0; mf<8; mf++){
    int ch0 = mf*16 + g*4;
    float bias[4];
    #pragma unroll
    for (int j=0;j<4;j++) bias[j] = b2s[ch0+j];
    float vm[4] = {0.f,0.f,0.f,0.f};
    #pragma unroll
    for (int nf=0; nf<2; nf++){
      int n = n_base + nf*16 + p15;
      float v[4];
      #pragma unroll
      for (int j=0;j<4;j++){
        v[j] = fmaxf(acc[mf][nf][j] + bias[j], 0.f);
        vm[j] = fmaxf(vm[j], v[j]);
        x0[((size_t)(b*256 + ch0 + j))*4096 + n] = v[j];
      }
      unsigned lo = (unsigned)f2bf(v[0]) | ((unsigned)f2bf(v[1])<<16);
      unsigned hi = (unsigned)f2bf(v[2]) | ((unsigned)f2bf(v[3])<<16);
      *(uint2*)&h2b[((size_t)(b*4096 + n))*128 + ch0] = make_uint2(lo, hi);
    }
    #pragma unroll
    for (int j=0;j<4;j++){
      float m = vm[j];
      m = fmaxf(m, __shfl_xor(m,1));
      m = fmaxf(m, __shfl_xor(m,2));
      m = fmaxf(m, __shfl_xor(m,4));
      m = fmaxf(m, __shfl_xor(m,8));
      if (p15==0) atomicMax(&gmax[ch0+j], __float_as_uint(m));
    }
  }
  __syncthreads();
  if (tid < 128) atomicMax(&gfeatU[b*128 + tid], gmax[tid]);   // 8KB target, r13-proven
}

// ---- gcon wave-per-output: 128 blocks x 8 outputs; reads 8KB gfeatU ----
__global__ __launch_bounds__(256) void gcon_k(
    const unsigned* __restrict__ gfeatU,
    const float* __restrict__ w3, const float* __restrict__ b3,
    float* __restrict__ gcon)
{
  __shared__ float gf[2048];
  int tid = threadIdx.x, bid = blockIdx.x;
  for (int i=tid;i<2048;i+=256) gf[i] = __uint_as_float(gfeatU[i]);
  __syncthreads();
  int w = tid >> 6, lane = tid & 63;
  #pragma unroll
  for (int j=0;j<2;j++){
    int o = bid*8 + w*2 + j;
    float2 wv = *(const float2*)&w3[(size_t)o*256 + 128 + lane*2];  // coalesced
    float bias = b3[o];
    #pragma unroll
    for (int b=0;b<16;b++){
      float v = gf[b*128 + lane*2]*wv.x + gf[b*128 + lane*2 + 1]*wv.y;
      #pragma unroll
      for (int off=32; off; off>>=1) v += __shfl_xor(v, off);
      if (lane==0) gcon[b*1024+o] = bias + v;
    }
  }
}

// ------- fused: conv3 MFMA+pool (bids 0..511) | x0 gfeat-bcast (512..4607) -------
__global__ __launch_bounds__(512) void conv3_bcast(
    const unsigned short* __restrict__ h2b, const unsigned short* __restrict__ w3b,
    const float* __restrict__ gcon, unsigned* __restrict__ pooled,
    const unsigned* __restrict__ gfeatU, float* __restrict__ x0)
{
  __shared__ unsigned short Al[128*128];
  __shared__ unsigned short Bl[128*128];
  int tid = threadIdx.x, bid = blockIdx.x;
  if (bid >= 512){
    unsigned U = (unsigned)(bid-512)*512 + tid;   // over 2,097,152 float4
    int n4 = U & 1023, c = (U >> 10) & 127, b = U >> 17;
    float g = __uint_as_float(gfeatU[b*128+c]);
    float4 v = {g,g,g,g};
    ((float4*)x0)[(((size_t)b*256 + 128 + c)*4096)/4 + n4] = v;
    return;
  }
  int mt = bid & 31, b = bid >> 5;
  {
    const uint4* src = (const uint4*)(h2b + ((size_t)b*4096 + mt*128)*128);
    #pragma unroll
    for (int i=0;i<4;i++){
      int idx = i*512 + tid;
      int r = idx>>4, kc = idx&15;
      uint4 v = src[idx];
      int byte = (r*256 + kc*16) ^ ((r&7)<<4);
      *(uint4*)((char*)Al + byte) = v;
    }
  }
  int lane = tid & 63, wid = tid >> 6;
  int wm = wid >> 2, wn = wid & 3;
  int mbase = wm*64, nbase = wn*32;
  for (int nt=0; nt<8; nt++){
    if (nt) __syncthreads();
    {
      #pragma unroll
      for (int i=0;i<4;i++){
        int idx = i*512 + tid;
        int c = idx>>4, kc = idx&15;
        uint4 v = *(const uint4*)(w3b + ((size_t)(nt*128+c)*256 + kc*8));
        int byte = (c*256 + kc*16) ^ ((c&7)<<4);
        *(uint4*)((char*)Bl + byte) = v;
      }
    }
    __syncthreads();
    f32x4 acc[4][2] = {};
    #pragma unroll
    for (int ks=0;ks<4;ks++){
      int kb = (ks*32 + (lane>>4)*8)*2;
      short8 af[4], bfr[2];
      #pragma unroll
      for (int mi=0;mi<4;mi++){
        int row = mbase + mi*16 + (lane&15);
        af[mi] = *(const short8*)((const char*)Al + ((row*256 + kb) ^ ((row&7)<<4)));
      }
      #pragma unroll
      for (int ni=0;ni<2;ni++){
        int col = nbase + ni*16 + (lane&15);
        bfr[ni] = *(const short8*)((const char*)Bl + ((col*256 + kb) ^ ((col&7)<<4)));
      }
      #pragma unroll
      for (int mi=0;mi<4;mi++){
        #pragma unroll
        for (int ni=0;ni<2;ni++)
          acc[mi][ni] = __builtin_amdgcn_mfma_f32_16x16x32_bf16(af[mi], bfr[ni], acc[mi][ni], 0,0,0);
      }
    }
    #pragma unroll
    for (int ni=0;ni<2;ni++){
      int o = nt*128 + nbase + ni*16 + (lane&15);
      float g = gcon[b*1024 + o];
      float m = 0.f;
      #pragma unroll
      for (int mi=0;mi<4;mi++){
        f32x4 a = acc[mi][ni];
        #pragma unroll
        for (int r=0;r<4;r++){ float v = a[r]+g; m = fmaxf(m, v); }
      }
      m = fmaxf(m, 0.f);
      m = fmaxf(m, __shfl_xor(m, 16));
      m = fmaxf(m, __shfl_xor(m, 32));
      if (lane < 16) atomicMax(&pooled[(size_t)b*1024+o], __float_as_uint(m));
    }
  }
}

// ---- fallback (small ws) kernels ----
__global__ __launch_bounds__(256) void conv12_f32(
    const float* __restrict__ in_pc,
    const float* __restrict__ w1, const float* __restrict__ b1,
    const float* __restrict__ w2, const float* __restrict__ b2,
    float* __restrict__ x0, unsigned* __restrict__ gfeatU)
{
  __shared__ unsigned gmax[32];
  int tid = threadIdx.x;
  if (tid < 32) gmax[tid] = 0u;
  __syncthreads();
  int idx = blockIdx.x*256 + tid;
  int b = idx >> 12, n = idx & 4095;
  int gy = blockIdx.y;
  int lane = tid & 63;
  const float* p = in_pc + (size_t)idx*3;
  float px=p[0], py=p[1], pz=p[2];
  float h1[64];
  #pragma unroll
  for (int c=0;c<64;c++)
    h1[c] = fmaxf(w1[c*3]*px + w1[c*3+1]*py + w1[c*3+2]*pz + b1[c], 0.f);
  #pragma unroll
  for (int j=0;j<32;j++){
    int o = gy*32 + j;
    float a = b2[o];
    #pragma unroll
    for (int c=0;c<64;c++) a += w2[o*64+c]*h1[c];
    a = fmaxf(a, 0.f);
    x0[((size_t)b*256 + o)*4096 + n] = a;
    float m = a;
    #pragma unroll
    for (int off=32; off; off>>=1) m = fmaxf(m, __shfl_xor(m, off));
    if (lane==0) atomicMax(&gmax[j], __float_as_uint(m));
  }
  __syncthreads();
  if (tid < 32) atomicMax(&gfeatU[b*128 + gy*32 + tid], gmax[tid]);
}

__global__ __launch_bounds__(256) void bcast_gcon(
    const unsigned* __restrict__ gfeatU, float* __restrict__ x0,
    const float* __restrict__ w3, const float* __restrict__ b3,
    float* __restrict__ gcon)
{
  __shared__ float gf[2048];
  int tid = threadIdx.x;
  if (blockIdx.x < 8192){
    unsigned U = blockIdx.x*256 + tid;
    int n4 = U & 1023, c = (U >> 10) & 127, b = U >> 17;
    float g = __uint_as_float(gfeatU[b*128+c]);
    float4 v = {g,g,g,g};
    ((float4*)x0)[(((size_t)b*256 + 128 + c)*4096)/4 + n4] = v;
  } else {
    for (int i=tid;i<2048;i+=256) gf[i] = __uint_as_float(gfeatU[i]);
    __syncthreads();
    int o = (blockIdx.x - 8192)*256 + tid;
    float bias = b3[o];
    float acc[16];
    #pragma unroll
    for (int b=0;b<16;b++) acc[b]=bias;
    for (int c=0;c<128;c++){
      float wv = w3[(size_t)o*256 + 128 + c];
      #pragma unroll
      for (int b=0;b<16;b++) acc[b] += gf[b*128+c]*wv;
    }
    #pragma unroll
    for (int b=0;b<16;b++) gcon[b*1024+o] = acc[b];
  }
}

__global__ __launch_bounds__(256) void conv3n(
    const float* __restrict__ x0, const unsigned* __restrict__ gfeatU,
    const float* __restrict__ w3, const float* __restrict__ b3,
    unsigned* __restrict__ pooled)
{
  __shared__ float wrow[8][256];
  int b = blockIdx.x >> 7, og = (blockIdx.x & 127)*8, tid = threadIdx.x;
  for (int i=tid;i<2048;i+=256){ int j=i>>8, c=i&255; wrow[j][c]=w3[(size_t)(og+j)*256+c]; }
  __syncthreads();
  float gconst[8];
  #pragma unroll
  for (int j=0;j<8;j++){
    float g = b3[og+j];
    for (int c=0;c<128;c++) g += __uint_as_float(gfeatU[b*128+c])*wrow[j][128+c];
    gconst[j] = g;
  }
  const float* xb = x0 + (size_t)b*256*4096;
  float m[8];
  #pragma unroll
  for (int j=0;j<8;j++) m[j]=0.f;
  for (int n=tid;n<4096;n+=256){
    float v[8];
    #pragma unroll
    for (int j=0;j<8;j++) v[j]=gconst[j];
    for (int c=0;c<128;c++){
      float xv = xb[(size_t)c*4096 + n];
      #pragma unroll
      for (int j=0;j<8;j++) v[j] += xv*wrow[j][c];
    }
    #pragma unroll
    for (int j=0;j<8;j++) m[j] = fmaxf(m[j], v[j]);
  }
  #pragma unroll
  for (int j=0;j<8;j++){
    float v = m[j];
    for (int off=32; off; off>>=1) v = fmaxf(v, __shfl_xor(v, off));
    if ((tid&63)==0) atomicMax(&pooled[(size_t)b*1024+og+j], __float_as_uint(v));
  }
}

// ------- fc: one wave per output o, all 16 batches in registers -------
template<bool RELU>
__global__ __launch_bounds__(256) void fc_wave16(
    const float* __restrict__ A, const float* __restrict__ W,
    const float* __restrict__ bias, float* __restrict__ out,
    float* __restrict__ out2, int K, int O)
{
  int lane = threadIdx.x & 63, w = threadIdx.x >> 6;
  int o = blockIdx.x*4 + w;
  const float* Wr = W + (size_t)o*K;
  float acc[16];
  #pragma unroll
  for (int b=0;b<16;b++) acc[b]=0.f;
  for (int k = lane*4; k < K; k += 256){
    float4 wv = *(const float4*)&Wr[k];
    #pragma unroll
    for (int b=0;b<16;b++){
      float4 av = *(const float4*)&A[(size_t)b*K + k];
      acc[b] += wv.x*av.x + wv.y*av.y + wv.z*av.z + wv.w*av.w;
    }
  }
  #pragma unroll
  for (int b=0;b<16;b++){
    float v = acc[b];
    #pragma unroll
    for (int off=32; off; off>>=1) v += __shfl_xor(v, off);
    if (lane==0){
      v += bias[o];
      if (RELU) v = fmaxf(v, 0.f);
      out[(size_t)b*O+o] = v;
      if (out2) out2[(size_t)b*O+o] = v;
    }
  }
}

// ---------------- LayerNorm ----------------
__global__ __launch_bounds__(256) void lnorm(
    const float* __restrict__ h3, const float* __restrict__ g,
    const float* __restrict__ be, float* __restrict__ outf,
    float* __restrict__ outb)
{
  int b = blockIdx.x, tid = threadIdx.x;
  const float* x = h3 + b*6144;
  float s=0.f, s2=0.f;
  for (int i=tid;i<6144;i+=256){ float v=x[i]; s+=v; s2+=v*v; }
  for (int off=32; off; off>>=1){ s += __shfl_xor(s,off); s2 += __shfl_xor(s2,off); }
  __shared__ float red[8];
  int lane = tid&63, wid = tid>>6;
  if (lane==0){ red[wid]=s; red[4+wid]=s2; }
  __syncthreads();
  s  = red[0]+red[1]+red[2]+red[3];
  s2 = red[4]+red[5]+red[6]+red[7];
  float mu  = s * (1.f/6144.f);
  float var = s2 * (1.f/6144.f) - mu*mu;
  float inv = rsqrtf(var + 1e-5f);
  for (int i=tid;i<6144;i+=256){
    float v = (x[i]-mu)*inv*g[i] + be[i];
    outf[b*6144+i] = v;
    outb[b*6144+i] = v;
  }
}

// ---- chamfer: 512 targets staged/block; packed dual-FP32 FMA ----
__global__ __launch_bounds__(256) void chamfer_all(
    const float* __restrict__ in_pc, const float* __restrict__ opc,
    unsigned* __restrict__ d1m, unsigned* __restrict__ d2m)
{
  __shared__ float sX[512], sY[512], sZ[512], sQ[512];
  int bid = blockIdx.x, tid = threadIdx.x;
  const float* stage;
  const float* qry;
  unsigned* outp;
  if (bid < 1024){
    int xt = bid & 15, b = (bid >> 4) & 15, mt = bid >> 8;
    stage = opc + b*6144 + mt*1536;
    qry   = in_pc + ((size_t)b*4096 + xt*256 + tid)*3;
    outp  = d1m + b*4096 + xt*256 + tid;
  } else {
    int r = bid - 1024;
    int xt = r & 7, b = (r >> 3) & 15, nt = r >> 7;
    stage = in_pc + ((size_t)b*4096 + nt*512)*3;
    qry   = opc + b*6144 + (xt*256 + tid)*3;
    outp  = d2m + b*2048 + xt*256 + tid;
  }
  for (int s = tid; s < 512; s += 256){
    const float* S = stage + s*3;
    float x=S[0], y=S[1], z=S[2];
    sX[s]=-2.f*x; sY[s]=-2.f*y; sZ[s]=-2.f*z; sQ[s]=x*x+y*y+z*z;
  }
  __syncthreads();
  float qx=qry[0], qy=qry[1], qz=qry[2];
  float p2 = qx*qx + qy*qy + qz*qz;
  f32x2 qxv = {qx,qx}, qyv = {qy,qy}, qzv = {qz,qz};
  float ma=3.0e38f, mb=3.0e38f, mc=3.0e38f, md=3.0e38f;
  #pragma unroll 4
  for (int i=0;i<128;i++){
    f32x4 X = *(const f32x4*)&sX[i*4];
    f32x4 Y = *(const f32x4*)&sY[i*4];
    f32x4 Z = *(const f32x4*)&sZ[i*4];
    f32x4 Q = *(const f32x4*)&sQ[i*4];
    f32x2 t0 = __builtin_shufflevector(Q,Q,0,1);
    f32x2 t1 = __builtin_shufflevector(Q,Q,2,3);
    t0 = pkfma(qzv, __builtin_shufflevector(Z,Z,0,1), t0);
    t1 = pkfma(qzv, __builtin_shufflevector(Z,Z,2,3), t1);
    t0 = pkfma(qyv, __builtin_shufflevector(Y,Y,0,1), t0);
    t1 = pkfma(qyv, __builtin_shufflevector(Y,Y,2,3), t1);
    t0 = pkfma(qxv, __builtin_shufflevector(X,X,0,1), t0);
    t1 = pkfma(qxv, __builtin_shufflevector(X,X,2,3), t1);
    ma = fminf(ma, t0.x); mb = fminf(mb, t0.y);
    mc = fminf(mc, t1.x); md = fminf(md, t1.y);
  }
  float d = fmaxf(p2 + fminf(fminf(ma,mb), fminf(mc,md)), 0.f);
  atomicMin(outp, __float_as_uint(d));
}

// ---- fused deterministic loss reduction (96 partials + last-block finish) ----
__global__ __launch_bounds__(256) void sum_loss(
    const unsigned* __restrict__ d1m, const unsigned* __restrict__ d2m,
    float* __restrict__ ps, int* __restrict__ cnt, float* __restrict__ out)
{
  int bid = blockIdx.x, tid = threadIdx.x;
  __shared__ float red[4];
  __shared__ int last;
  {
    const unsigned* src = (bid<64) ? (d1m + bid*1024) : (d2m + (size_t)(bid-64)*1024);
    float s = 0.f;
    for (int i=tid;i<1024;i+=256) s += __uint_as_float(src[i]);
    for (int off=32; off; off>>=1) s += __shfl_xor(s,off);
    if ((tid&63)==0) red[tid>>6]=s;
    __syncthreads();
    if (tid==0){
      ps[bid] = red[0]+red[1]+red[2]+red[3];
      __threadfence();
      last = (atomicAdd(cnt, 1) == 95);
    }
    __syncthreads();
  }
  if (!last) return;
  __threadfence();
  float v = 0.f;
  if (tid < 64) v = ps[tid] * (1.0f/65536.0f);
  else if (tid < 96) v = ps[tid] * (1.0f/32768.0f);
  for (int off=32; off; off>>=1) v += __shfl_xor(v,off);
  __syncthreads();
  if ((tid&63)==0) red[tid>>6]=v;
  __syncthreads();
  if (tid==0) out[0] = red[0]+red[1]+red[2]+red[3];
}

// ---------------- launch ----------------
extern "C" void kernel_launch(void* const* d_in, const int* in_sizes, int n_in,
                              void* d_out, int out_size, void* d_ws, size_t ws_size,
                              hipStream_t stream)
{
  (void)in_sizes; (void)n_in; (void)out_size;
  const float* in_pc = (const float*)d_in[0];
  const float* w1   = (const float*)d_in[1];
  const float* b1   = (const float*)d_in[2];
  const float* w2   = (const float*)d_in[3];
  const float* b2   = (const float*)d_in[4];
  const float* w3   = (const float*)d_in[5];
  const float* b3   = (const float*)d_in[6];
  const float* wenc = (const float*)d_in[7];
  const float* benc = (const float*)d_in[8];
  const float* wf1  = (const float*)d_in[9];
  const float* bfc1 = (const float*)d_in[10];
  const float* wf2  = (const float*)d_in[11];
  const float* bfc2 = (const float*)d_in[12];
  const float* wf3  = (const float*)d_in[13];
  const float* bfc3 = (const float*)d_in[14];
  const float* lng  = (const float*)d_in[15];
  const float* lnb  = (const float*)d_in[16];
  float* out = (float*)d_out;

  bool big = ws_size >= (size_t)(H2_BYTES + 3*1024*1024);
  char* ws = (char*)d_ws;
  unsigned short* h2b = (unsigned short*)ws;
  char* small = ws + (big ? H2_BYTES : 0);

  unsigned* gfeatU = (unsigned*)(small + OFF_GFEAT);
  float* pooled = (float*)(small + OFF_POOL);
  float* gcon = (float*)(small + OFF_GCON);
  float* emb  = (float*)(small + OFF_EMB);
  float* hd1  = (float*)(small + OFF_HD1);
  float* hd2  = (float*)(small + OFF_HD2);
  float* h3   = (float*)(small + OFF_H3);
  float* opc  = (float*)(small + OFF_OPC);
  unsigned* d1m = (unsigned*)(small + OFF_D1M);
  unsigned* d2m = (unsigned*)(small + OFF_D2M);
  float* ps   = (float*)(small + OFF_PS);
  unsigned short* w3b = (unsigned short*)(small + OFF_W3BF);
  int* cnt = (int*)(small + OFF_CNT);

  if (big){
    conv12_mfma<<<1139, 256, 0, stream>>>(in_pc, w1, b1, w2, b2, out, h2b, gfeatU,
                                          w3, (unsigned*)w3b, small);
    gcon_k<<<128, 256, 0, stream>>>(gfeatU, w3, b3, gcon);
    conv3_bcast<<<4608, 512, 0, stream>>>(h2b, w3b, gcon, (unsigned*)pooled,
                                          gfeatU, out);
  } else {
    hipMemsetAsync(small + OFF_GFEAT, 0, 8192 + 65536, stream);
    hipMemsetAsync(small + OFF_D1M, 0x7F, 262144 + 131072, stream);
    hipMemsetAsync(small + OFF_CNT, 0, 4, stream);
    conv12_f32<<<dim3(256,4), 256, 0, stream>>>(in_pc, w1, b1, w2, b2, out, gfeatU);
    bcast_gcon<<<8196, 256, 0, stream>>>(gfeatU, out, w3, b3, gcon);
    conv3n<<<2048, 256, 0, stream>>>(out, gfeatU, w3, b3, (unsigned*)pooled);
  }
  fc_wave16<false><<<64,   256, 0, stream>>>(pooled, wenc, benc, emb, out + OUT_EMB, 1024, 256);
  fc_wave16<true ><<<128,  256, 0, stream>>>(emb, wf1, bfc1, hd1, nullptr, 256, 512);
  fc_wave16<true ><<<256,  256, 0, stream>>>(hd1, wf2, bfc2, hd2, nullptr, 512, 1024);
  fc_wave16<false><<<1536, 256, 0, stream>>>(hd2, wf3, bfc3, h3, nullptr, 1024, 6144);
  lnorm<<<16, 256, 0, stream>>>(h3, lng, lnb, opc, out + OUT_OPC);
  chamfer_all<<<2048, 256, 0, stream>>>(in_pc, opc, d1m, d2m);
  sum_loss<<<96, 256, 0, stream>>>(d1m, d2m, ps, cnt, out + OUT_LOSS);
}

// Round 24
// 145.007 us; speedup vs baseline: 1.3999x; 1.0754x over previous
//
#include <hip/hip_runtime.h>

// output element offsets (f32 elements)
#define OUT_X0   0
#define OUT_EMB  16777216
#define OUT_OPC  16781312
#define OUT_LOSS 16879616

// small-buffer byte offsets (relative to `small` base)
#define OFF_GFEAT 0            // 8192     u32 float-bits [16][128]
#define OFF_POOL  8192         // 65536    u32 float-bits [16][1024]
#define OFF_GCON  73728        // 65536    f32 [16][1024]
#define OFF_EMB   139264       // 16384    f32 [16][256]
#define OFF_HD1   155648       // 32768    f32 [16][512]
#define OFF_HD2   188416       // 65536    f32 [16][1024]
#define OFF_H3    253952       // 393216   f32 [16][6144]
#define OFF_OPC   647168       // 393216   f32 [16][6144]
#define OFF_D1M   1040384      // 262144   u32 [16][4096]
#define OFF_D2M   1302528      // 131072   u32 [16][2048]
#define OFF_PS    1433600      // 384      f32 [96]
#define OFF_W3BF  1433984      // 524288   bf16 w3 [1024][256]
#define OFF_CNT   1958272      // 4        int counter
#define H2_BYTES  (16u*1024*1024)   // bf16 h2 [65536][128] at ws+0 (big path)

typedef short short8 __attribute__((ext_vector_type(8)));
typedef float f32x4  __attribute__((ext_vector_type(4)));
typedef float f32x2  __attribute__((ext_vector_type(2)));

__device__ __forceinline__ unsigned short f2bf(float f){
  unsigned u = __float_as_uint(f);
  return (unsigned short)((u + 0x7FFFu + ((u >> 16) & 1u)) >> 16);
}

// packed dual-FP32 FMA: d = a*b + c per half (CDNA VOP3P)
__device__ __forceinline__ f32x2 pkfma(f32x2 a, f32x2 b, f32x2 c){
  f32x2 d;
  asm("v_pk_fma_f32 %0, %1, %2, %3" : "=v"(d) : "v"(a), "v"(b), "v"(c));
  return d;
}

// ------- conv1+conv2 via MFMA + folded w3-cvt + folded init -------
// bid 0..114: init fills. 115..626: conv (16 b x 32 pt-tiles). 627..1138: w3 cvt.
__global__ __launch_bounds__(256) void conv12_mfma(
    const float* __restrict__ in_pc,
    const float* __restrict__ w1, const float* __restrict__ b1,
    const float* __restrict__ w2, const float* __restrict__ b2,
    float* __restrict__ x0, unsigned short* __restrict__ h2b,
    unsigned* __restrict__ gfeatU,
    const float* __restrict__ w3, unsigned* __restrict__ w3bf,
    char* __restrict__ small)
{
  __shared__ unsigned short w2s[8192];   // [128 ch][64 c] bf16, XOR-swizzled
  __shared__ unsigned short h1s[8192];   // [128 pt][64 c] bf16, XOR-swizzled
  __shared__ float b2s[128];
  __shared__ unsigned gmax[128];
  int tid = threadIdx.x, bid = blockIdx.x;
  if (bid < 115){  // init: gfeat+pooled=0, d1m/d2m=0x7F, cnt=0
    int i = bid*256 + tid;
    if (i < 4608) ((uint4*)(small + OFF_GFEAT))[i] = make_uint4(0u,0u,0u,0u);
    int j = i - 4608;
    if (j >= 0 && j < 24576)
      ((uint4*)(small + OFF_D1M))[j] =
        make_uint4(0x7F7F7F7Fu,0x7F7F7F7Fu,0x7F7F7F7Fu,0x7F7F7F7Fu);
    if (i == 29184) *(int*)(small + OFF_CNT) = 0;
    return;
  }
  if (bid >= 627){   // w3 f32->bf16: 512*256 float2 = 131072
    int i = (bid-627)*256 + tid;
    float2 v = ((const float2*)w3)[i];
    w3bf[i] = (unsigned)f2bf(v.x) | ((unsigned)f2bf(v.y)<<16);
    return;
  }
  int cb = bid - 115;
  int b = cb >> 5;
  int nt0 = (cb & 31)*128;
  for (int i = tid; i < 2048; i += 256){
    int ch = i >> 4, q = i & 15;
    float4 v = ((const float4*)w2)[i];
    unsigned lo = (unsigned)f2bf(v.x) | ((unsigned)f2bf(v.y)<<16);
    unsigned hi = (unsigned)f2bf(v.z) | ((unsigned)f2bf(v.w)<<16);
    int byte = (ch*128 + q*8) ^ ((ch&7)<<4);
    *(uint2*)((char*)w2s + byte) = make_uint2(lo, hi);
  }
  if (tid < 128){ b2s[tid] = b2[tid]; gmax[tid] = 0u; }
  { // h1: 2 threads per point, 32 channels each
    int pt = tid & 127;
    int qb = (tid >> 7) * 16;
    int idx = b*4096 + nt0 + pt;
    const float* p = in_pc + (size_t)idx*3;
    float px=p[0], py=p[1], pz=p[2];
    unsigned hp[16];
    #pragma unroll
    for (int q=0;q<16;q++){
      int c = (qb + q)*2;
      float v0 = fmaxf(fmaf(w1[c*3  ],px, fmaf(w1[c*3+1],py, fmaf(w1[c*3+2],pz, b1[c  ]))), 0.f);
      float v1 = fmaxf(fmaf(w1[c*3+3],px, fmaf(w1[c*3+4],py, fmaf(w1[c*3+5],pz, b1[c+1]))), 0.f);
      hp[q] = (unsigned)f2bf(v0) | ((unsigned)f2bf(v1)<<16);
    }
    #pragma unroll
    for (int t=0;t<4;t++){
      int byte = (pt*128 + qb*4 + t*16) ^ ((pt&7)<<4);
      *(uint4*)((char*)h1s + byte) = make_uint4(hp[t*4],hp[t*4+1],hp[t*4+2],hp[t*4+3]);
    }
  }
  __syncthreads();
  int lane = tid & 63, w = tid >> 6;
  int g = lane >> 4, p15 = lane & 15;
  f32x4 acc[8][2] = {};
  #pragma unroll
  for (int ks=0; ks<2; ks++){
    int kb = (ks*32 + g*8)*2;
    short8 bfr[2];
    #pragma unroll
    for (int nf=0;nf<2;nf++){
      int pt = w*32 + nf*16 + p15;
      bfr[nf] = *(const short8*)((const char*)h1s + ((pt*128 + kb) ^ ((pt&7)<<4)));
    }
    #pragma unroll
    for (int mf=0;mf<8;mf++){
      int ch = mf*16 + p15;
      short8 af = *(const short8*)((const char*)w2s + ((ch*128 + kb) ^ ((ch&7)<<4)));
      acc[mf][0] = __builtin_amdgcn_mfma_f32_16x16x32_bf16(af, bfr[0], acc[mf][0], 0,0,0);
      acc[mf][1] = __builtin_amdgcn_mfma_f32_16x16x32_bf16(af, bfr[1], acc[mf][1], 0,0,0);
    }
  }
  int n_base = nt0 + w*32;
  #pragma unroll
  for (int mf=0; mf<8; mf++){
    int ch0 = mf*16 + g*4;
    float bias[4];
    #pragma unroll
    for (int j=0;j<4;j++) bias[j] = b2s[ch0+j];
    float vm[4] = {0.f,0.f,0.f,0.f};
    #pragma unroll
    for (int nf=0; nf<2; nf++){
      int n = n_base + nf*16 + p15;
      float v[4];
      #pragma unroll
      for (int j=0;j<4;j++){
        v[j] = fmaxf(acc[mf][nf][j] + bias[j], 0.f);
        vm[j] = fmaxf(vm[j], v[j]);
        x0[((size_t)(b*256 + ch0 + j))*4096 + n] = v[j];
      }
      unsigned lo = (unsigned)f2bf(v[0]) | ((unsigned)f2bf(v[1])<<16);
      unsigned hi = (unsigned)f2bf(v[2]) | ((unsigned)f2bf(v[3])<<16);
      *(uint2*)&h2b[((size_t)(b*4096 + n))*128 + ch0] = make_uint2(lo, hi);
    }
    #pragma unroll
    for (int j=0;j<4;j++){
      float m = vm[j];
      m = fmaxf(m, __shfl_xor(m,1));
      m = fmaxf(m, __shfl_xor(m,2));
      m = fmaxf(m, __shfl_xor(m,4));
      m = fmaxf(m, __shfl_xor(m,8));
      if (p15==0) atomicMax(&gmax[ch0+j], __float_as_uint(m));
    }
  }
  __syncthreads();
  if (tid < 128) atomicMax(&gfeatU[b*128 + tid], gmax[tid]);   // 8KB target, r13-proven
}

// ---- gcon wave-per-output: 128 blocks x 8 outputs; reads 8KB gfeatU ----
__global__ __launch_bounds__(256) void gcon_k(
    const unsigned* __restrict__ gfeatU,
    const float* __restrict__ w3, const float* __restrict__ b3,
    float* __restrict__ gcon)
{
  __shared__ float gf[2048];
  int tid = threadIdx.x, bid = blockIdx.x;
  for (int i=tid;i<2048;i+=256) gf[i] = __uint_as_float(gfeatU[i]);
  __syncthreads();
  int w = tid >> 6, lane = tid & 63;
  #pragma unroll
  for (int j=0;j<2;j++){
    int o = bid*8 + w*2 + j;
    float2 wv = *(const float2*)&w3[(size_t)o*256 + 128 + lane*2];  // coalesced
    float bias = b3[o];
    #pragma unroll
    for (int b=0;b<16;b++){
      float v = gf[b*128 + lane*2]*wv.x + gf[b*128 + lane*2 + 1]*wv.y;
      #pragma unroll
      for (int off=32; off; off>>=1) v += __shfl_xor(v, off);
      if (lane==0) gcon[b*1024+o] = bias + v;
    }
  }
}

// ------- fused: conv3 MFMA+pool (bids 0..511) | x0 gfeat-bcast (512..4607) -------
__global__ __launch_bounds__(512) void conv3_bcast(
    const unsigned short* __restrict__ h2b, const unsigned short* __restrict__ w3b,
    const float* __restrict__ gcon, unsigned* __restrict__ pooled,
    const unsigned* __restrict__ gfeatU, float* __restrict__ x0)
{
  __shared__ unsigned short Al[128*128];
  __shared__ unsigned short Bl[128*128];
  int tid = threadIdx.x, bid = blockIdx.x;
  if (bid >= 512){
    unsigned U = (unsigned)(bid-512)*512 + tid;   // over 2,097,152 float4
    int n4 = U & 1023, c = (U >> 10) & 127, b = U >> 17;
    float g = __uint_as_float(gfeatU[b*128+c]);
    float4 v = {g,g,g,g};
    ((float4*)x0)[(((size_t)b*256 + 128 + c)*4096)/4 + n4] = v;
    return;
  }
  int mt = bid & 31, b = bid >> 5;
  {
    const uint4* src = (const uint4*)(h2b + ((size_t)b*4096 + mt*128)*128);
    #pragma unroll
    for (int i=0;i<4;i++){
      int idx = i*512 + tid;
      int r = idx>>4, kc = idx&15;
      uint4 v = src[idx];
      int byte = (r*256 + kc*16) ^ ((r&7)<<4);
      *(uint4*)((char*)Al + byte) = v;
    }
  }
  int lane = tid & 63, wid = tid >> 6;
  int wm = wid >> 2, wn = wid & 3;
  int mbase = wm*64, nbase = wn*32;
  for (int nt=0; nt<8; nt++){
    if (nt) __syncthreads();
    {
      #pragma unroll
      for (int i=0;i<4;i++){
        int idx = i*512 + tid;
        int c = idx>>4, kc = idx&15;
        uint4 v = *(const uint4*)(w3b + ((size_t)(nt*128+c)*256 + kc*8));
        int byte = (c*256 + kc*16) ^ ((c&7)<<4);
        *(uint4*)((char*)Bl + byte) = v;
      }
    }
    __syncthreads();
    f32x4 acc[4][2] = {};
    #pragma unroll
    for (int ks=0;ks<4;ks++){
      int kb = (ks*32 + (lane>>4)*8)*2;
      short8 af[4], bfr[2];
      #pragma unroll
      for (int mi=0;mi<4;mi++){
        int row = mbase + mi*16 + (lane&15);
        af[mi] = *(const short8*)((const char*)Al + ((row*256 + kb) ^ ((row&7)<<4)));
      }
      #pragma unroll
      for (int ni=0;ni<2;ni++){
        int col = nbase + ni*16 + (lane&15);
        bfr[ni] = *(const short8*)((const char*)Bl + ((col*256 + kb) ^ ((col&7)<<4)));
      }
      #pragma unroll
      for (int mi=0;mi<4;mi++){
        #pragma unroll
        for (int ni=0;ni<2;ni++)
          acc[mi][ni] = __builtin_amdgcn_mfma_f32_16x16x32_bf16(af[mi], bfr[ni], acc[mi][ni], 0,0,0);
      }
    }
    #pragma unroll
    for (int ni=0;ni<2;ni++){
      int o = nt*128 + nbase + ni*16 + (lane&15);
      float g = gcon[b*1024 + o];
      float m = 0.f;
      #pragma unroll
      for (int mi=0;mi<4;mi++){
        f32x4 a = acc[mi][ni];
        #pragma unroll
        for (int r=0;r<4;r++){ float v = a[r]+g; m = fmaxf(m, v); }
      }
      m = fmaxf(m, 0.f);
      m = fmaxf(m, __shfl_xor(m, 16));
      m = fmaxf(m, __shfl_xor(m, 32));
      if (lane < 16) atomicMax(&pooled[(size_t)b*1024+o], __float_as_uint(m));
    }
  }
}

// ---- fallback (small ws) kernels ----
__global__ __launch_bounds__(256) void conv12_f32(
    const float* __restrict__ in_pc,
    const float* __restrict__ w1, const float* __restrict__ b1,
    const float* __restrict__ w2, const float* __restrict__ b2,
    float* __restrict__ x0, unsigned* __restrict__ gfeatU)
{
  __shared__ unsigned gmax[32];
  int tid = threadIdx.x;
  if (tid < 32) gmax[tid] = 0u;
  __syncthreads();
  int idx = blockIdx.x*256 + tid;
  int b = idx >> 12, n = idx & 4095;
  int gy = blockIdx.y;
  int lane = tid & 63;
  const float* p = in_pc + (size_t)idx*3;
  float px=p[0], py=p[1], pz=p[2];
  float h1[64];
  #pragma unroll
  for (int c=0;c<64;c++)
    h1[c] = fmaxf(w1[c*3]*px + w1[c*3+1]*py + w1[c*3+2]*pz + b1[c], 0.f);
  #pragma unroll
  for (int j=0;j<32;j++){
    int o = gy*32 + j;
    float a = b2[o];
    #pragma unroll
    for (int c=0;c<64;c++) a += w2[o*64+c]*h1[c];
    a = fmaxf(a, 0.f);
    x0[((size_t)b*256 + o)*4096 + n] = a;
    float m = a;
    #pragma unroll
    for (int off=32; off; off>>=1) m = fmaxf(m, __shfl_xor(m, off));
    if (lane==0) atomicMax(&gmax[j], __float_as_uint(m));
  }
  __syncthreads();
  if (tid < 32) atomicMax(&gfeatU[b*128 + gy*32 + tid], gmax[tid]);
}

__global__ __launch_bounds__(256) void bcast_gcon(
    const unsigned* __restrict__ gfeatU, float* __restrict__ x0,
    const float* __restrict__ w3, const float* __restrict__ b3,
    float* __restrict__ gcon)
{
  __shared__ float gf[2048];
  int tid = threadIdx.x;
  if (blockIdx.x < 8192){
    unsigned U = blockIdx.x*256 + tid;
    int n4 = U & 1023, c = (U >> 10) & 127, b = U >> 17;
    float g = __uint_as_float(gfeatU[b*128+c]);
    float4 v = {g,g,g,g};
    ((float4*)x0)[(((size_t)b*256 + 128 + c)*4096)/4 + n4] = v;
  } else {
    for (int i=tid;i<2048;i+=256) gf[i] = __uint_as_float(gfeatU[i]);
    __syncthreads();
    int o = (blockIdx.x - 8192)*256 + tid;
    float bias = b3[o];
    float acc[16];
    #pragma unroll
    for (int b=0;b<16;b++) acc[b]=bias;
    for (int c=0;c<128;c++){
      float wv = w3[(size_t)o*256 + 128 + c];
      #pragma unroll
      for (int b=0;b<16;b++) acc[b] += gf[b*128+c]*wv;
    }
    #pragma unroll
    for (int b=0;b<16;b++) gcon[b*1024+o] = acc[b];
  }
}

__global__ __launch_bounds__(256) void conv3n(
    const float* __restrict__ x0, const unsigned* __restrict__ gfeatU,
    const float* __restrict__ w3, const float* __restrict__ b3,
    unsigned* __restrict__ pooled)
{
  __shared__ float wrow[8][256];
  int b = blockIdx.x >> 7, og = (blockIdx.x & 127)*8, tid = threadIdx.x;
  for (int i=tid;i<2048;i+=256){ int j=i>>8, c=i&255; wrow[j][c]=w3[(size_t)(og+j)*256+c]; }
  __syncthreads();
  float gconst[8];
  #pragma unroll
  for (int j=0;j<8;j++){
    float g = b3[og+j];
    for (int c=0;c<128;c++) g += __uint_as_float(gfeatU[b*128+c])*wrow[j][128+c];
    gconst[j] = g;
  }
  const float* xb = x0 + (size_t)b*256*4096;
  float m[8];
  #pragma unroll
  for (int j=0;j<8;j++) m[j]=0.f;
  for (int n=tid;n<4096;n+=256){
    float v[8];
    #pragma unroll
    for (int j=0;j<8;j++) v[j]=gconst[j];
    for (int c=0;c<128;c++){
      float xv = xb[(size_t)c*4096 + n];
      #pragma unroll
      for (int j=0;j<8;j++) v[j] += xv*wrow[j][c];
    }
    #pragma unroll
    for (int j=0;j<8;j++) m[j] = fmaxf(m[j], v[j]);
  }
  #pragma unroll
  for (int j=0;j<8;j++){
    float v = m[j];
    for (int off=32; off; off>>=1) v = fmaxf(v, __shfl_xor(v, off));
    if ((tid&63)==0) atomicMax(&pooled[(size_t)b*1024+og+j], __float_as_uint(v));
  }
}

// ------- fc: one wave per output o, all 16 batches in registers -------
template<bool RELU>
__global__ __launch_bounds__(256) void fc_wave16(
    const float* __restrict__ A, const float* __restrict__ W,
    const float* __restrict__ bias, float* __restrict__ out,
    float* __restrict__ out2, int K, int O)
{
  int lane = threadIdx.x & 63, w = threadIdx.x >> 6;
  int o = blockIdx.x*4 + w;
  const float* Wr = W + (size_t)o*K;
  float acc[16];
  #pragma unroll
  for (int b=0;b<16;b++) acc[b]=0.f;
  for (int k = lane*4; k < K; k += 256){
    float4 wv = *(const float4*)&Wr[k];
    #pragma unroll
    for (int b=0;b<16;b++){
      float4 av = *(const float4*)&A[(size_t)b*K + k];
      acc[b] += wv.x*av.x + wv.y*av.y + wv.z*av.z + wv.w*av.w;
    }
  }
  #pragma unroll
  for (int b=0;b<16;b++){
    float v = acc[b];
    #pragma unroll
    for (int off=32; off; off>>=1) v += __shfl_xor(v, off);
    if (lane==0){
      v += bias[o];
      if (RELU) v = fmaxf(v, 0.f);
      out[(size_t)b*O+o] = v;
      if (out2) out2[(size_t)b*O+o] = v;
    }
  }
}

// ---------------- LayerNorm ----------------
__global__ __launch_bounds__(256) void lnorm(
    const float* __restrict__ h3, const float* __restrict__ g,
    const float* __restrict__ be, float* __restrict__ outf,
    float* __restrict__ outb)
{
  int b = blockIdx.x, tid = threadIdx.x;
  const float* x = h3 + b*6144;
  float s=0.f, s2=0.f;
  for (int i=tid;i<6144;i+=256){ float v=x[i]; s+=v; s2+=v*v; }
  for (int off=32; off; off>>=1){ s += __shfl_xor(s,off); s2 += __shfl_xor(s2,off); }
  __shared__ float red[8];
  int lane = tid&63, wid = tid>>6;
  if (lane==0){ red[wid]=s; red[4+wid]=s2; }
  __syncthreads();
  s  = red[0]+red[1]+red[2]+red[3];
  s2 = red[4]+red[5]+red[6]+red[7];
  float mu  = s * (1.f/6144.f);
  float var = s2 * (1.f/6144.f) - mu*mu;
  float inv = rsqrtf(var + 1e-5f);
  for (int i=tid;i<6144;i+=256){
    float v = (x[i]-mu)*inv*g[i] + be[i];
    outf[b*6144+i] = v;
    outb[b*6144+i] = v;
  }
}

// ---- chamfer v5: 2 queries/thread; 512 targets staged; pkfma ----
// bids 0..511: d1 (8 q-chunks x 16 b x 4 target-chunks of 512)
// bids 512..1023: d2 (4 q-chunks x 16 b x 8 target-chunks of 512)
__global__ __launch_bounds__(256) void chamfer_all(
    const float* __restrict__ in_pc, const float* __restrict__ opc,
    unsigned* __restrict__ d1m, unsigned* __restrict__ d2m)
{
  __shared__ float sX[512], sY[512], sZ[512], sQ[512];
  int bid = blockIdx.x, tid = threadIdx.x;
  const float* stage;
  const float* qry;       // base of this block's 512 queries
  unsigned* outp;
  if (bid < 512){
    int xt = bid & 7, b = (bid >> 3) & 15, mt = bid >> 7;
    stage = opc + b*6144 + mt*1536;
    qry   = in_pc + ((size_t)b*4096 + xt*512)*3;
    outp  = d1m + b*4096 + xt*512;
  } else {
    int r = bid - 512;
    int xt = r & 3, b = (r >> 2) & 15, nt = r >> 6;
    stage = in_pc + ((size_t)b*4096 + nt*512)*3;
    qry   = opc + b*6144 + xt*512*3;
    outp  = d2m + b*2048 + xt*512;
  }
  for (int s = tid; s < 512; s += 256){
    const float* S = stage + s*3;
    float x=S[0], y=S[1], z=S[2];
    sX[s]=-2.f*x; sY[s]=-2.f*y; sZ[s]=-2.f*z; sQ[s]=x*x+y*y+z*z;
  }
  __syncthreads();
  const float* q0p = qry + tid*3;
  const float* q1p = qry + (256+tid)*3;
  float q0x=q0p[0], q0y=q0p[1], q0z=q0p[2];
  float q1x=q1p[0], q1y=q1p[1], q1z=q1p[2];
  float p20 = q0x*q0x + q0y*q0y + q0z*q0z;
  float p21 = q1x*q1x + q1y*q1y + q1z*q1z;
  f32x2 q0xv={q0x,q0x}, q0yv={q0y,q0y}, q0zv={q0z,q0z};
  f32x2 q1xv={q1x,q1x}, q1yv={q1y,q1y}, q1zv={q1z,q1z};
  float a0=3.0e38f, b0=3.0e38f, c0=3.0e38f, d0=3.0e38f;
  float a1=3.0e38f, b1=3.0e38f, c1=3.0e38f, d1v=3.0e38f;
  #pragma unroll 2
  for (int i=0;i<128;i++){
    f32x4 X = *(const f32x4*)&sX[i*4];
    f32x4 Y = *(const f32x4*)&sY[i*4];
    f32x4 Z = *(const f32x4*)&sZ[i*4];
    f32x4 Q = *(const f32x4*)&sQ[i*4];
    f32x2 Xl = __builtin_shufflevector(X,X,0,1), Xh = __builtin_shufflevector(X,X,2,3);
    f32x2 Yl = __builtin_shufflevector(Y,Y,0,1), Yh = __builtin_shufflevector(Y,Y,2,3);
    f32x2 Zl = __builtin_shufflevector(Z,Z,0,1), Zh = __builtin_shufflevector(Z,Z,2,3);
    f32x2 Ql = __builtin_shufflevector(Q,Q,0,1), Qh = __builtin_shufflevector(Q,Q,2,3);
    f32x2 t0, t1;
    // query 0
    t0 = pkfma(q0zv, Zl, Ql); t1 = pkfma(q0zv, Zh, Qh);
    t0 = pkfma(q0yv, Yl, t0); t1 = pkfma(q0yv, Yh, t1);
    t0 = pkfma(q0xv, Xl, t0); t1 = pkfma(q0xv, Xh, t1);
    a0 = fminf(a0, t0.x); b0 = fminf(b0, t0.y);
    c0 = fminf(c0, t1.x); d0 = fminf(d0, t1.y);
    // query 1
    t0 = pkfma(q1zv, Zl, Ql); t1 = pkfma(q1zv, Zh, Qh);
    t0 = pkfma(q1yv, Yl, t0); t1 = pkfma(q1yv, Yh, t1);
    t0 = pkfma(q1xv, Xl, t0); t1 = pkfma(q1xv, Xh, t1);
    a1 = fminf(a1, t0.x); b1 = fminf(b1, t0.y);
    c1 = fminf(c1, t1.x); d1v = fminf(d1v, t1.y);
  }
  float r0 = fmaxf(p20 + fminf(fminf(a0,b0), fminf(c0,d0)), 0.f);
  float r1 = fmaxf(p21 + fminf(fminf(a1,b1), fminf(c1,d1v)), 0.f);
  atomicMin(outp + tid,       __float_as_uint(r0));
  atomicMin(outp + 256 + tid, __float_as_uint(r1));
}

// ---- fused deterministic loss reduction (96 partials + last-block finish) ----
__global__ __launch_bounds__(256) void sum_loss(
    const unsigned* __restrict__ d1m, const unsigned* __restrict__ d2m,
    float* __restrict__ ps, int* __restrict__ cnt, float* __restrict__ out)
{
  int bid = blockIdx.x, tid = threadIdx.x;
  __shared__ float red[4];
  __shared__ int last;
  {
    const unsigned* src = (bid<64) ? (d1m + bid*1024) : (d2m + (size_t)(bid-64)*1024);
    float s = 0.f;
    for (int i=tid;i<1024;i+=256) s += __uint_as_float(src[i]);
    for (int off=32; off; off>>=1) s += __shfl_xor(s,off);
    if ((tid&63)==0) red[tid>>6]=s;
    __syncthreads();
    if (tid==0){
      ps[bid] = red[0]+red[1]+red[2]+red[3];
      __threadfence();
      last = (atomicAdd(cnt, 1) == 95);
    }
    __syncthreads();
  }
  if (!last) return;
  __threadfence();
  float v = 0.f;
  if (tid < 64) v = ps[tid] * (1.0f/65536.0f);
  else if (tid < 96) v = ps[tid] * (1.0f/32768.0f);
  for (int off=32; off; off>>=1) v += __shfl_xor(v,off);
  __syncthreads();
  if ((tid&63)==0) red[tid>>6]=v;
  __syncthreads();
  if (tid==0) out[0] = red[0]+red[1]+red[2]+red[3];
}

// ---------------- launch ----------------
extern "C" void kernel_launch(void* const* d_in, const int* in_sizes, int n_in,
                              void* d_out, int out_size, void* d_ws, size_t ws_size,
                              hipStream_t stream)
{
  (void)in_sizes; (void)n_in; (void)out_size;
  const float* in_pc = (const float*)d_in[0];
  const float* w1   = (const float*)d_in[1];
  const float* b1   = (const float*)d_in[2];
  const float* w2   = (const float*)d_in[3];
  const float* b2   = (const float*)d_in[4];
  const float* w3   = (const float*)d_in[5];
  const float* b3   = (const float*)d_in[6];
  const float* wenc = (const float*)d_in[7];
  const float* benc = (const float*)d_in[8];
  const float* wf1  = (const float*)d_in[9];
  const float* bfc1 = (const float*)d_in[10];
  const float* wf2  = (const float*)d_in[11];
  const float* bfc2 = (const float*)d_in[12];
  const float* wf3  = (const float*)d_in[13];
  const float* bfc3 = (const float*)d_in[14];
  const float* lng  = (const float*)d_in[15];
  const float* lnb  = (const float*)d_in[16];
  float* out = (float*)d_out;

  bool big = ws_size >= (size_t)(H2_BYTES + 3*1024*1024);
  char* ws = (char*)d_ws;
  unsigned short* h2b = (unsigned short*)ws;
  char* small = ws + (big ? H2_BYTES : 0);

  unsigned* gfeatU = (unsigned*)(small + OFF_GFEAT);
  float* pooled = (float*)(small + OFF_POOL);
  float* gcon = (float*)(small + OFF_GCON);
  float* emb  = (float*)(small + OFF_EMB);
  float* hd1  = (float*)(small + OFF_HD1);
  float* hd2  = (float*)(small + OFF_HD2);
  float* h3   = (float*)(small + OFF_H3);
  float* opc  = (float*)(small + OFF_OPC);
  unsigned* d1m = (unsigned*)(small + OFF_D1M);
  unsigned* d2m = (unsigned*)(small + OFF_D2M);
  float* ps   = (float*)(small + OFF_PS);
  unsigned short* w3b = (unsigned short*)(small + OFF_W3BF);
  int* cnt = (int*)(small + OFF_CNT);

  if (big){
    conv12_mfma<<<1139, 256, 0, stream>>>(in_pc, w1, b1, w2, b2, out, h2b, gfeatU,
                                          w3, (unsigned*)w3b, small);
    gcon_k<<<128, 256, 0, stream>>>(gfeatU, w3, b3, gcon);
    conv3_bcast<<<4608, 512, 0, stream>>>(h2b, w3b, gcon, (unsigned*)pooled,
                                          gfeatU, out);
  } else {
    hipMemsetAsync(small + OFF_GFEAT, 0, 8192 + 65536, stream);
    hipMemsetAsync(small + OFF_D1M, 0x7F, 262144 + 131072, stream);
    hipMemsetAsync(small + OFF_CNT, 0, 4, stream);
    conv12_f32<<<dim3(256,4), 256, 0, stream>>>(in_pc, w1, b1, w2, b2, out, gfeatU);
    bcast_gcon<<<8196, 256, 0, stream>>>(gfeatU, out, w3, b3, gcon);
    conv3n<<<2048, 256, 0, stream>>>(out, gfeatU, w3, b3, (unsigned*)pooled);
  }
  fc_wave16<false><<<64,   256, 0, stream>>>(pooled, wenc, benc, emb, out + OUT_EMB, 1024, 256);
  fc_wave16<true ><<<128,  256, 0, stream>>>(emb, wf1, bfc1, hd1, nullptr, 256, 512);
  fc_wave16<true ><<<256,  256, 0, stream>>>(hd1, wf2, bfc2, hd2, nullptr, 512, 1024);
  fc_wave16<false><<<1536, 256, 0, stream>>>(hd2, wf3, bfc3, h3, nullptr, 1024, 6144);
  lnorm<<<16, 256, 0, stream>>>(h3, lng, lnb, opc, out + OUT_OPC);
  chamfer_all<<<1024, 256, 0, stream>>>(in_pc, opc, d1m, d2m);
  sum_loss<<<96, 256, 0, stream>>>(d1m, d2m, ps, cnt, out + OUT_LOSS);
}